// Round 3
// baseline (152.317 us; speedup 1.0000x reference)
//
#include <hip/hip_runtime.h>

// GSICell: out[n] = sum_{e: dst(e)=n} eattr[src%100, dst%100] * <feat38(x_i,x_j), wc_eff>
//                 + <feat12(x[n]), wf_eff>
// wc_eff[k] = c_mask[k] * (wc2[k] - wc2[k+38])   (concat([C,-C]) @ w collapse)
// wf_eff[k] = f_mask[k] * (wf2[k] - wf2[k+12])
// R2 bug: edge_index is delivered as int32 (harness: "integer -> const int*");
// reading it as int64 ran 2x past the buffer -> HSA fault -> abort.

#define NCL 38
#define NFL 12

__device__ __forceinline__ float frcp(float v) { return __builtin_amdgcn_rcpf(v); }

// _safe_inv: 1.0 / (|v|<eps ? sign(v)*eps : v), eps=1e-2, sign(0)=+1
__device__ __forceinline__ float safe_inv(float v) {
    float den = (fabsf(v) < 0.01f) ? ((v >= 0.0f) ? 0.01f : -0.01f) : v;
    return frcp(den);
}

// Node library: [1, sin, cos, x*sin, x, x^2, inv, inv^2, inv^3, tanh, sigmoid, relu]
// Also initializes d_out (poisoned 0xAA before each call).
__global__ void __launch_bounds__(256) node_kernel(
        const float* __restrict__ x,
        const float* __restrict__ f_mask,
        const float* __restrict__ wf2,
        float* __restrict__ out, int n) {
    __shared__ float wf[NFL];
    if (threadIdx.x < NFL)
        wf[threadIdx.x] = f_mask[threadIdx.x] * (wf2[threadIdx.x] - wf2[threadIdx.x + NFL]);
    __syncthreads();
    int i = blockIdx.x * blockDim.x + threadIdx.x;
    if (i >= n) return;
    float v  = x[i];
    float sv = __sinf(v), cv = __cosf(v);
    float iv = safe_inv(v);
    float e  = __expf(v), e2 = e * e;
    float th = (e2 - 1.f) * frcp(e2 + 1.f);   // tanh
    float sg = e * frcp(e + 1.f);             // sigmoid
    float F = wf[0] + wf[1] * sv + wf[2] * cv + wf[3] * (v * sv)
            + wf[4] * v + wf[5] * (v * v)
            + wf[6] * iv + wf[7] * (iv * iv) + wf[8] * (iv * iv * iv)
            + wf[9] * th + wf[10] * sg + wf[11] * fmaxf(v, 0.f);
    out[i] = F;   // F_COEF = 1.0
}

// 38-term edge library dotted with wc_eff on the fly (w = LDS pointer).
__device__ __forceinline__ float edge_msg(float xi, float xj, const float* w) {
    float d = xj - xi;
    float s = xj + xi;
    float acc;
    // polys p=1,2: x_i^p, x_j^p, d^p
    acc  = w[0] * xi + w[1] * xj + w[2] * d;
    acc += w[3] * (xi * xi) + w[4] * (xj * xj) + w[5] * (d * d);
    // neg powers n=1,2: inv(xi), inv(xj), inv(d), inv(s)
    float ii = safe_inv(xi), ij = safe_inv(xj), id = safe_inv(d), is = safe_inv(s);
    acc += w[6] * ii + w[7] * ij + w[8] * id + w[9] * is;
    acc += w[10] * (ii * ii) + w[11] * (ij * ij) + w[12] * (id * id) + w[13] * (is * is);
    // trig
    float sd = __sinf(d), cd = __cosf(d);
    float ss = __sinf(s), cs = __cosf(s);
    float si = __sinf(xi), ci = __cosf(xi);
    float sj = __sinf(xj), cj = __cosf(xj);
    acc += w[14] * sd + w[15] * cd + w[16] * ss + w[17] * cs;
    acc += w[18] * si + w[19] * ci + w[20] * sj + w[21] * cj;
    // cross terms
    acc += w[22] * (xi * xj) + w[23] * (xi * sj) + w[24] * (xj * si) + w[25] * (sd * cs);
    // activations: tanh, sigmoid, relu for (xi, xj, d, s) — one exp each
    {
        float e = __expf(xi), e2 = e * e;
        acc += w[26] * ((e2 - 1.f) * frcp(e2 + 1.f)) + w[27] * (e * frcp(e + 1.f)) + w[28] * fmaxf(xi, 0.f);
    }
    {
        float e = __expf(xj), e2 = e * e;
        acc += w[29] * ((e2 - 1.f) * frcp(e2 + 1.f)) + w[30] * (e * frcp(e + 1.f)) + w[31] * fmaxf(xj, 0.f);
    }
    {
        float e = __expf(d), e2 = e * e;
        acc += w[32] * ((e2 - 1.f) * frcp(e2 + 1.f)) + w[33] * (e * frcp(e + 1.f)) + w[34] * fmaxf(d, 0.f);
    }
    {
        float e = __expf(s), e2 = e * e;
        acc += w[35] * ((e2 - 1.f) * frcp(e2 + 1.f)) + w[36] * (e * frcp(e + 1.f)) + w[37] * fmaxf(s, 0.f);
    }
    return acc;
}

__global__ void __launch_bounds__(256) edge_kernel(
        const float* __restrict__ x,
        const int* __restrict__ ei,           // [2, E] int32: row0 = src, row1 = dst
        const float* __restrict__ eattr,      // [100, 100]
        const float* __restrict__ c_mask,
        const float* __restrict__ wc2,
        float* __restrict__ out,
        int E) {
    __shared__ float w[NCL];
    if (threadIdx.x < NCL)
        w[threadIdx.x] = c_mask[threadIdx.x] * (wc2[threadIdx.x] - wc2[threadIdx.x + NCL]);
    __syncthreads();

    int t  = blockIdx.x * blockDim.x + threadIdx.x;
    int e0 = 4 * t;
    if (e0 + 3 < E) {
        int4 s4 = *(const int4*)(ei + e0);        // 16B coalesced (offset 16*t)
        int4 d4 = *(const int4*)(ei + E + e0);    // E % 4 == 0 -> 16B aligned
        int ss[4] = {s4.x, s4.y, s4.z, s4.w};
        int dd[4] = {d4.x, d4.y, d4.z, d4.w};
#pragma unroll
        for (int k = 0; k < 4; ++k) {
            int s = ss[k], d = dd[k];
            float m  = edge_msg(x[d], x[s], w);
            float ea = eattr[(s % 100) * 100 + (d % 100)];
            unsafeAtomicAdd(out + d, ea * m);     // hw global_atomic_add_f32
        }
    } else {
        for (int e = e0; e < E; ++e) {
            int s = ei[e], d = ei[E + e];
            float m  = edge_msg(x[d], x[s], w);
            float ea = eattr[(s % 100) * 100 + (d % 100)];
            unsafeAtomicAdd(out + d, ea * m);
        }
    }
}

extern "C" void kernel_launch(void* const* d_in, const int* in_sizes, int n_in,
                              void* d_out, int out_size, void* d_ws, size_t ws_size,
                              hipStream_t stream) {
    // inputs: 0=t(scalar,unused), 1=x[N], 2=edge_index[2*E] int32, 3=c_mask[38],
    //         4=f_mask[12], 5=wc_2[76], 6=wf_2[24], 7=edge_attr_all[100*100]
    const float* x      = (const float*)d_in[1];
    const int*   ei     = (const int*)d_in[2];
    const float* c_mask = (const float*)d_in[3];
    const float* f_mask = (const float*)d_in[4];
    const float* wc2    = (const float*)d_in[5];
    const float* wf2    = (const float*)d_in[6];
    const float* eattr  = (const float*)d_in[7];
    float* out = (float*)d_out;

    int N = in_sizes[1];
    int E = in_sizes[2] / 2;

    node_kernel<<<(N + 255) / 256, 256, 0, stream>>>(x, f_mask, wf2, out, N);
    int threads = (E + 3) / 4;
    edge_kernel<<<(threads + 255) / 256, 256, 0, stream>>>(x, ei, eattr, c_mask, wc2, out, E);
}

// Round 4
// 107.602 us; speedup vs baseline: 1.4156x; 1.4156x over previous
//
#include <hip/hip_runtime.h>

// GSICell. out[n] = sum_{e: dst=n} eattr[s%100, d%100] * <feat38(x_i,x_j), wc_eff> + <feat12(x[n]), wf_eff>
// wc_eff[k] = c_mask[k]*(wc2[k]-wc2[k+38]); wf_eff[k] = f_mask[k]*(wf2[k]-wf2[k+12])
//
// R3 post-mortem: 1M device-scope fp32 atomics onto 10k addresses = fabric-bound
// (WRITE_SIZE 30.6MB = 1M x 32B write-through, 12.3 G atomics/s, VALUBusy 5%).
// R4: per-block LDS accumulator (out fits: 40KB) + ds_add_f32, flush to d_ws with
// plain stores, 2-pass tree reduction. Zero global atomics. Fallback to the
// R3 atomic path if ws_size is too small (deterministic per session).

#define NCL 38
#define NFL 12
#define NMAX 10240
#define GRP 8

__device__ __forceinline__ float frcp(float v) { return __builtin_amdgcn_rcpf(v); }

// _safe_inv: 1.0 / (|v|<eps ? sign(v)*eps : v), eps=1e-2, sign(0)=+1
__device__ __forceinline__ float safe_inv(float v) {
    float den = (fabsf(v) < 0.01f) ? ((v >= 0.0f) ? 0.01f : -0.01f) : v;
    return frcp(den);
}

// 38-term edge library dotted with wc_eff on the fly (w = LDS pointer).
__device__ __forceinline__ float edge_msg(float xi, float xj, const float* w) {
    float d = xj - xi;
    float s = xj + xi;
    float acc;
    acc  = w[0] * xi + w[1] * xj + w[2] * d;
    acc += w[3] * (xi * xi) + w[4] * (xj * xj) + w[5] * (d * d);
    float ii = safe_inv(xi), ij = safe_inv(xj), id = safe_inv(d), is = safe_inv(s);
    acc += w[6] * ii + w[7] * ij + w[8] * id + w[9] * is;
    acc += w[10] * (ii * ii) + w[11] * (ij * ij) + w[12] * (id * id) + w[13] * (is * is);
    float sd = __sinf(d), cd = __cosf(d);
    float ss = __sinf(s), cs = __cosf(s);
    float si = __sinf(xi), ci = __cosf(xi);
    float sj = __sinf(xj), cj = __cosf(xj);
    acc += w[14] * sd + w[15] * cd + w[16] * ss + w[17] * cs;
    acc += w[18] * si + w[19] * ci + w[20] * sj + w[21] * cj;
    acc += w[22] * (xi * xj) + w[23] * (xi * sj) + w[24] * (xj * si) + w[25] * (sd * cs);
    {
        float e = __expf(xi), e2 = e * e;
        acc += w[26] * ((e2 - 1.f) * frcp(e2 + 1.f)) + w[27] * (e * frcp(e + 1.f)) + w[28] * fmaxf(xi, 0.f);
    }
    {
        float e = __expf(xj), e2 = e * e;
        acc += w[29] * ((e2 - 1.f) * frcp(e2 + 1.f)) + w[30] * (e * frcp(e + 1.f)) + w[31] * fmaxf(xj, 0.f);
    }
    {
        float e = __expf(d), e2 = e * e;
        acc += w[32] * ((e2 - 1.f) * frcp(e2 + 1.f)) + w[33] * (e * frcp(e + 1.f)) + w[34] * fmaxf(d, 0.f);
    }
    {
        float e = __expf(s), e2 = e * e;
        acc += w[35] * ((e2 - 1.f) * frcp(e2 + 1.f)) + w[36] * (e * frcp(e + 1.f)) + w[37] * fmaxf(s, 0.f);
    }
    return acc;
}

// Node library: [1, sin, cos, x*sin, x, x^2, inv, inv^2, inv^3, tanh, sigmoid, relu]
__device__ __forceinline__ float node_F(float v, const float* wf) {
    float sv = __sinf(v), cv = __cosf(v);
    float iv = safe_inv(v);
    float e  = __expf(v), e2 = e * e;
    float th = (e2 - 1.f) * frcp(e2 + 1.f);
    float sg = e * frcp(e + 1.f);
    return wf[0] + wf[1] * sv + wf[2] * cv + wf[3] * (v * sv)
         + wf[4] * v + wf[5] * (v * v)
         + wf[6] * iv + wf[7] * (iv * iv) + wf[8] * (iv * iv * iv)
         + wf[9] * th + wf[10] * sg + wf[11] * fmaxf(v, 0.f);
}

// ---------------- Fast path: LDS accumulation, no global atomics ----------------

__global__ void __launch_bounds__(256) edge_lds_kernel(
        const float* __restrict__ x,
        const int* __restrict__ ei,           // [2, E] int32
        const float* __restrict__ eattr,      // [100, 100]
        const float* __restrict__ c_mask,
        const float* __restrict__ wc2,
        float* __restrict__ scratch,          // [gridDim.x, N] partials
        int E, int N) {
    __shared__ float w[NCL];
    __shared__ float acc[NMAX];
    if (threadIdx.x < NCL)
        w[threadIdx.x] = c_mask[threadIdx.x] * (wc2[threadIdx.x] - wc2[threadIdx.x + NCL]);
    for (int i = threadIdx.x; i < N; i += 256) acc[i] = 0.f;
    __syncthreads();

    const int T = gridDim.x * 256;
    const int t = blockIdx.x * 256 + threadIdx.x;
    const int E4 = E & ~3;
    for (int e0 = 4 * t; e0 < E4; e0 += 4 * T) {
        int4 s4 = *(const int4*)(ei + e0);        // 16B coalesced
        int4 d4 = *(const int4*)(ei + E + e0);    // E4-aligned
        int ss[4] = {s4.x, s4.y, s4.z, s4.w};
        int dd[4] = {d4.x, d4.y, d4.z, d4.w};
#pragma unroll
        for (int k = 0; k < 4; ++k) {
            int s = ss[k], d = dd[k];
            float m  = edge_msg(x[d], x[s], w);
            float ea = eattr[(s % 100) * 100 + (d % 100)];
            atomicAdd(&acc[d], ea * m);           // ds_add_f32 (LDS hw atomic)
        }
    }
    if (t == 0) {                                  // tail (E % 4)
        for (int e = E4; e < E; ++e) {
            int s = ei[e], d = ei[E + e];
            float m  = edge_msg(x[d], x[s], w);
            float ea = eattr[(s % 100) * 100 + (d % 100)];
            atomicAdd(&acc[d], ea * m);
        }
    }
    __syncthreads();
    float* dst = scratch + (size_t)blockIdx.x * N;
    for (int i = threadIdx.x; i < N; i += 256) dst[i] = acc[i];   // coalesced
}

// pass1: s2[g][n] = sum over this group's B/GRP partials
__global__ void __launch_bounds__(256) reduce1_kernel(
        const float* __restrict__ scratch, float* __restrict__ s2, int N, int B) {
    int n = blockIdx.x * 256 + threadIdx.x;
    if (n >= N) return;
    int per = B / GRP;
    const float* p = scratch + (size_t)(blockIdx.y * per) * N + n;
    float sum = 0.f;
    for (int b = 0; b < per; ++b) sum += p[(size_t)b * N];        // coalesced per iter
    s2[(size_t)blockIdx.y * N + n] = sum;
}

// pass2: out[n] = F(x[n]) + sum_g s2[g][n]   (also initializes poisoned d_out)
__global__ void __launch_bounds__(256) reduce2_kernel(
        const float* __restrict__ x,
        const float* __restrict__ f_mask,
        const float* __restrict__ wf2,
        const float* __restrict__ s2,
        float* __restrict__ out, int N) {
    __shared__ float wf[NFL];
    if (threadIdx.x < NFL)
        wf[threadIdx.x] = f_mask[threadIdx.x] * (wf2[threadIdx.x] - wf2[threadIdx.x + NFL]);
    __syncthreads();
    int n = blockIdx.x * 256 + threadIdx.x;
    if (n >= N) return;
    float sum = node_F(x[n], wf);
    for (int g = 0; g < GRP; ++g) sum += s2[(size_t)g * N + n];
    out[n] = sum;
}

// ---------------- Fallback path (R3, proven): global hw atomics ----------------

__global__ void __launch_bounds__(256) node_kernel(
        const float* __restrict__ x,
        const float* __restrict__ f_mask,
        const float* __restrict__ wf2,
        float* __restrict__ out, int n) {
    __shared__ float wf[NFL];
    if (threadIdx.x < NFL)
        wf[threadIdx.x] = f_mask[threadIdx.x] * (wf2[threadIdx.x] - wf2[threadIdx.x + NFL]);
    __syncthreads();
    int i = blockIdx.x * blockDim.x + threadIdx.x;
    if (i >= n) return;
    out[i] = node_F(x[i], wf);
}

__global__ void __launch_bounds__(256) edge_atomic_kernel(
        const float* __restrict__ x,
        const int* __restrict__ ei,
        const float* __restrict__ eattr,
        const float* __restrict__ c_mask,
        const float* __restrict__ wc2,
        float* __restrict__ out,
        int E) {
    __shared__ float w[NCL];
    if (threadIdx.x < NCL)
        w[threadIdx.x] = c_mask[threadIdx.x] * (wc2[threadIdx.x] - wc2[threadIdx.x + NCL]);
    __syncthreads();
    int t  = blockIdx.x * blockDim.x + threadIdx.x;
    int e0 = 4 * t;
    if (e0 + 3 < E) {
        int4 s4 = *(const int4*)(ei + e0);
        int4 d4 = *(const int4*)(ei + E + e0);
        int ss[4] = {s4.x, s4.y, s4.z, s4.w};
        int dd[4] = {d4.x, d4.y, d4.z, d4.w};
#pragma unroll
        for (int k = 0; k < 4; ++k) {
            int s = ss[k], d = dd[k];
            float m  = edge_msg(x[d], x[s], w);
            float ea = eattr[(s % 100) * 100 + (d % 100)];
            unsafeAtomicAdd(out + d, ea * m);
        }
    } else {
        for (int e = e0; e < E; ++e) {
            int s = ei[e], d = ei[E + e];
            float m  = edge_msg(x[d], x[s], w);
            float ea = eattr[(s % 100) * 100 + (d % 100)];
            unsafeAtomicAdd(out + d, ea * m);
        }
    }
}

extern "C" void kernel_launch(void* const* d_in, const int* in_sizes, int n_in,
                              void* d_out, int out_size, void* d_ws, size_t ws_size,
                              hipStream_t stream) {
    // inputs: 0=t, 1=x[N], 2=edge_index[2*E] int32, 3=c_mask[38], 4=f_mask[12],
    //         5=wc_2[76], 6=wf_2[24], 7=edge_attr_all[100*100]
    const float* x      = (const float*)d_in[1];
    const int*   ei     = (const int*)d_in[2];
    const float* c_mask = (const float*)d_in[3];
    const float* f_mask = (const float*)d_in[4];
    const float* wc2    = (const float*)d_in[5];
    const float* wf2    = (const float*)d_in[6];
    const float* eattr  = (const float*)d_in[7];
    float* out = (float*)d_out;

    int N = in_sizes[1];
    int E = in_sizes[2] / 2;

    // pick partial-count B by available scratch: (B + GRP) * N * 4 bytes needed
    int B = 0;
    if (N <= NMAX) {
        const int tiers[3] = {512, 256, 128};
        for (int i = 0; i < 3; ++i) {
            size_t need = ((size_t)tiers[i] + GRP) * (size_t)N * 4;
            if (ws_size >= need) { B = tiers[i]; break; }
        }
    }

    if (B) {
        float* scratch = (float*)d_ws;                 // [B][N]
        float* s2      = scratch + (size_t)B * N;      // [GRP][N]
        edge_lds_kernel<<<B, 256, 0, stream>>>(x, ei, eattr, c_mask, wc2, scratch, E, N);
        dim3 g1((N + 255) / 256, GRP);
        reduce1_kernel<<<g1, 256, 0, stream>>>(scratch, s2, N, B);
        reduce2_kernel<<<(N + 255) / 256, 256, 0, stream>>>(x, f_mask, wf2, s2, out, N);
    } else {
        node_kernel<<<(N + 255) / 256, 256, 0, stream>>>(x, f_mask, wf2, out, N);
        int threads = (E + 3) / 4;
        edge_atomic_kernel<<<(threads + 255) / 256, 256, 0, stream>>>(x, ei, eattr, c_mask, wc2, out, E);
    }
}

// Round 5
// 96.115 us; speedup vs baseline: 1.5847x; 1.1195x over previous
//
#include <hip/hip_runtime.h>

// GSICell. out[n] = sum_{e: dst=n} eattr[s%100, d%100] * <feat38(x_i,x_j), wc_eff> + <feat12(x[n]), wf_eff>
// wc_eff[k] = c_mask[k]*(wc2[k]-wc2[k+38]); wf_eff[k] = f_mask[k]*(wf2[k]-wf2[k+12])
//
// R4 post-mortem: harness re-poison of 256MiB d_ws = 43us fixed overhead (fillBufferAligned,
// 268MB @ 6.3TB/s); total overhead ~69us. Our kernels ~38us of the 107.6.
// R5: edge kernel B=256 blocks x 1024 threads (16 waves/CU, 2x latency hiding for the
// 3 random gathers/edge) and halved partial traffic (256x40KB=10.2MB). float4 init/flush.

#define NCL 38
#define NFL 12
#define NMAX 10240
#define GRP 8

__device__ __forceinline__ float frcp(float v) { return __builtin_amdgcn_rcpf(v); }

// _safe_inv: 1.0 / (|v|<eps ? sign(v)*eps : v), eps=1e-2, sign(0)=+1
__device__ __forceinline__ float safe_inv(float v) {
    float den = (fabsf(v) < 0.01f) ? ((v >= 0.0f) ? 0.01f : -0.01f) : v;
    return frcp(den);
}

// 38-term edge library dotted with wc_eff on the fly (w = LDS pointer).
__device__ __forceinline__ float edge_msg(float xi, float xj, const float* w) {
    float d = xj - xi;
    float s = xj + xi;
    float acc;
    acc  = w[0] * xi + w[1] * xj + w[2] * d;
    acc += w[3] * (xi * xi) + w[4] * (xj * xj) + w[5] * (d * d);
    float ii = safe_inv(xi), ij = safe_inv(xj), id = safe_inv(d), is = safe_inv(s);
    acc += w[6] * ii + w[7] * ij + w[8] * id + w[9] * is;
    acc += w[10] * (ii * ii) + w[11] * (ij * ij) + w[12] * (id * id) + w[13] * (is * is);
    float sd = __sinf(d), cd = __cosf(d);
    float ss = __sinf(s), cs = __cosf(s);
    float si = __sinf(xi), ci = __cosf(xi);
    float sj = __sinf(xj), cj = __cosf(xj);
    acc += w[14] * sd + w[15] * cd + w[16] * ss + w[17] * cs;
    acc += w[18] * si + w[19] * ci + w[20] * sj + w[21] * cj;
    acc += w[22] * (xi * xj) + w[23] * (xi * sj) + w[24] * (xj * si) + w[25] * (sd * cs);
    {
        float e = __expf(xi), e2 = e * e;
        acc += w[26] * ((e2 - 1.f) * frcp(e2 + 1.f)) + w[27] * (e * frcp(e + 1.f)) + w[28] * fmaxf(xi, 0.f);
    }
    {
        float e = __expf(xj), e2 = e * e;
        acc += w[29] * ((e2 - 1.f) * frcp(e2 + 1.f)) + w[30] * (e * frcp(e + 1.f)) + w[31] * fmaxf(xj, 0.f);
    }
    {
        float e = __expf(d), e2 = e * e;
        acc += w[32] * ((e2 - 1.f) * frcp(e2 + 1.f)) + w[33] * (e * frcp(e + 1.f)) + w[34] * fmaxf(d, 0.f);
    }
    {
        float e = __expf(s), e2 = e * e;
        acc += w[35] * ((e2 - 1.f) * frcp(e2 + 1.f)) + w[36] * (e * frcp(e + 1.f)) + w[37] * fmaxf(s, 0.f);
    }
    return acc;
}

// Node library: [1, sin, cos, x*sin, x, x^2, inv, inv^2, inv^3, tanh, sigmoid, relu]
__device__ __forceinline__ float node_F(float v, const float* wf) {
    float sv = __sinf(v), cv = __cosf(v);
    float iv = safe_inv(v);
    float e  = __expf(v), e2 = e * e;
    float th = (e2 - 1.f) * frcp(e2 + 1.f);
    float sg = e * frcp(e + 1.f);
    return wf[0] + wf[1] * sv + wf[2] * cv + wf[3] * (v * sv)
         + wf[4] * v + wf[5] * (v * v)
         + wf[6] * iv + wf[7] * (iv * iv) + wf[8] * (iv * iv * iv)
         + wf[9] * th + wf[10] * sg + wf[11] * fmaxf(v, 0.f);
}

// ---------------- Fast path: LDS accumulation, no global atomics ----------------

__global__ void __launch_bounds__(1024) edge_lds_kernel(
        const float* __restrict__ x,
        const int* __restrict__ ei,           // [2, E] int32
        const float* __restrict__ eattr,      // [100, 100]
        const float* __restrict__ c_mask,
        const float* __restrict__ wc2,
        float* __restrict__ scratch,          // [gridDim.x, N] partials
        int E, int N) {
    __shared__ float w[NCL];
    __shared__ float acc[NMAX];
    if (threadIdx.x < NCL)
        w[threadIdx.x] = c_mask[threadIdx.x] * (wc2[threadIdx.x] - wc2[threadIdx.x + NCL]);
    {   // vectorized zero-init (NMAX % 4 == 0)
        float4* a4 = (float4*)acc;
        for (int i = threadIdx.x; i < NMAX / 4; i += 1024) a4[i] = make_float4(0.f, 0.f, 0.f, 0.f);
    }
    __syncthreads();

    const int T = gridDim.x * 1024;
    const int t = blockIdx.x * 1024 + threadIdx.x;
    const int E4 = E & ~3;
    for (int e0 = 4 * t; e0 < E4; e0 += 4 * T) {
        int4 s4 = *(const int4*)(ei + e0);        // 16B coalesced
        int4 d4 = *(const int4*)(ei + E + e0);    // E4-aligned base (E % 4 == 0)
        int ss[4] = {s4.x, s4.y, s4.z, s4.w};
        int dd[4] = {d4.x, d4.y, d4.z, d4.w};
#pragma unroll
        for (int k = 0; k < 4; ++k) {
            int s = ss[k], d = dd[k];
            float m  = edge_msg(x[d], x[s], w);
            float ea = eattr[(s % 100) * 100 + (d % 100)];
            atomicAdd(&acc[d], ea * m);           // ds_add_f32 (LDS hw atomic)
        }
    }
    if (t == 0) {                                  // tail (E % 4), usually empty
        for (int e = E4; e < E; ++e) {
            int s = ei[e], d = ei[E + e];
            float m  = edge_msg(x[d], x[s], w);
            float ea = eattr[(s % 100) * 100 + (d % 100)];
            atomicAdd(&acc[d], ea * m);
        }
    }
    __syncthreads();
    // vectorized coalesced flush; N % 4 may be nonzero -> handle remainder
    float4* dst4 = (float4*)(scratch + (size_t)blockIdx.x * N);
    const float4* a4 = (const float4*)acc;
    int n4 = N / 4;
    for (int i = threadIdx.x; i < n4; i += 1024) dst4[i] = a4[i];
    for (int i = 4 * n4 + threadIdx.x; i < N; i += 1024)
        scratch[(size_t)blockIdx.x * N + i] = acc[i];
}

// pass1: s2[g][n] = sum over this group's B/GRP partial rows
__global__ void __launch_bounds__(256) reduce1_kernel(
        const float* __restrict__ scratch, float* __restrict__ s2, int N, int B) {
    int n = blockIdx.x * 256 + threadIdx.x;
    if (n >= N) return;
    int per = B / GRP;
    const float* p = scratch + (size_t)(blockIdx.y * per) * N + n;
    float sum = 0.f;
    for (int b = 0; b < per; ++b) sum += p[(size_t)b * N];        // coalesced per iter
    s2[(size_t)blockIdx.y * N + n] = sum;
}

// pass2: out[n] = F(x[n]) + sum_g s2[g][n]   (also initializes poisoned d_out)
__global__ void __launch_bounds__(256) reduce2_kernel(
        const float* __restrict__ x,
        const float* __restrict__ f_mask,
        const float* __restrict__ wf2,
        const float* __restrict__ s2,
        float* __restrict__ out, int N) {
    __shared__ float wf[NFL];
    if (threadIdx.x < NFL)
        wf[threadIdx.x] = f_mask[threadIdx.x] * (wf2[threadIdx.x] - wf2[threadIdx.x + NFL]);
    __syncthreads();
    int n = blockIdx.x * 256 + threadIdx.x;
    if (n >= N) return;
    float sum = node_F(x[n], wf);
#pragma unroll
    for (int g = 0; g < GRP; ++g) sum += s2[(size_t)g * N + n];
    out[n] = sum;
}

// ---------------- Fallback path (R3, proven): global hw atomics ----------------

__global__ void __launch_bounds__(256) node_kernel(
        const float* __restrict__ x,
        const float* __restrict__ f_mask,
        const float* __restrict__ wf2,
        float* __restrict__ out, int n) {
    __shared__ float wf[NFL];
    if (threadIdx.x < NFL)
        wf[threadIdx.x] = f_mask[threadIdx.x] * (wf2[threadIdx.x] - wf2[threadIdx.x + NFL]);
    __syncthreads();
    int i = blockIdx.x * blockDim.x + threadIdx.x;
    if (i >= n) return;
    out[i] = node_F(x[i], wf);
}

__global__ void __launch_bounds__(256) edge_atomic_kernel(
        const float* __restrict__ x,
        const int* __restrict__ ei,
        const float* __restrict__ eattr,
        const float* __restrict__ c_mask,
        const float* __restrict__ wc2,
        float* __restrict__ out,
        int E) {
    __shared__ float w[NCL];
    if (threadIdx.x < NCL)
        w[threadIdx.x] = c_mask[threadIdx.x] * (wc2[threadIdx.x] - wc2[threadIdx.x + NCL]);
    __syncthreads();
    int t  = blockIdx.x * blockDim.x + threadIdx.x;
    int e0 = 4 * t;
    if (e0 + 3 < E) {
        int4 s4 = *(const int4*)(ei + e0);
        int4 d4 = *(const int4*)(ei + E + e0);
        int ss[4] = {s4.x, s4.y, s4.z, s4.w};
        int dd[4] = {d4.x, d4.y, d4.z, d4.w};
#pragma unroll
        for (int k = 0; k < 4; ++k) {
            int s = ss[k], d = dd[k];
            float m  = edge_msg(x[d], x[s], w);
            float ea = eattr[(s % 100) * 100 + (d % 100)];
            unsafeAtomicAdd(out + d, ea * m);
        }
    } else {
        for (int e = e0; e < E; ++e) {
            int s = ei[e], d = ei[E + e];
            float m  = edge_msg(x[d], x[s], w);
            float ea = eattr[(s % 100) * 100 + (d % 100)];
            unsafeAtomicAdd(out + d, ea * m);
        }
    }
}

extern "C" void kernel_launch(void* const* d_in, const int* in_sizes, int n_in,
                              void* d_out, int out_size, void* d_ws, size_t ws_size,
                              hipStream_t stream) {
    // inputs: 0=t, 1=x[N], 2=edge_index[2*E] int32, 3=c_mask[38], 4=f_mask[12],
    //         5=wc_2[76], 6=wf_2[24], 7=edge_attr_all[100*100]
    const float* x      = (const float*)d_in[1];
    const int*   ei     = (const int*)d_in[2];
    const float* c_mask = (const float*)d_in[3];
    const float* f_mask = (const float*)d_in[4];
    const float* wc2    = (const float*)d_in[5];
    const float* wf2    = (const float*)d_in[6];
    const float* eattr  = (const float*)d_in[7];
    float* out = (float*)d_out;

    int N = in_sizes[1];
    int E = in_sizes[2] / 2;

    // pick partial-count B by available scratch: (B + GRP) * N * 4 bytes needed
    int B = 0;
    if (N <= NMAX) {
        const int tiers[3] = {256, 128, 64};   // B=256: 1 block/CU @ 1024 thr = 16 waves/CU
        for (int i = 0; i < 3; ++i) {
            size_t need = ((size_t)tiers[i] + GRP) * (size_t)N * 4;
            if (ws_size >= need) { B = tiers[i]; break; }
        }
    }

    if (B) {
        float* scratch = (float*)d_ws;                 // [B][N]
        float* s2      = scratch + (size_t)B * N;      // [GRP][N]
        edge_lds_kernel<<<B, 1024, 0, stream>>>(x, ei, eattr, c_mask, wc2, scratch, E, N);
        dim3 g1((N + 255) / 256, GRP);
        reduce1_kernel<<<g1, 256, 0, stream>>>(scratch, s2, N, B);
        reduce2_kernel<<<(N + 255) / 256, 256, 0, stream>>>(x, f_mask, wf2, s2, out, N);
    } else {
        node_kernel<<<(N + 255) / 256, 256, 0, stream>>>(x, f_mask, wf2, out, N);
        int threads = (E + 3) / 4;
        edge_atomic_kernel<<<(threads + 255) / 256, 256, 0, stream>>>(x, ei, eattr, c_mask, wc2, out, E);
    }
}

// Round 6
// 96.109 us; speedup vs baseline: 1.5848x; 1.0001x over previous
//
#include <hip/hip_runtime.h>

// GSICell. out[n] = sum_{e: dst=n} eattr[s%100, d%100] * <feat38(x_i,x_j), wc_eff> + <feat12(x[n]), wf_eff>
// wc_eff[k] = c_mask[k]*(wc2[k]-wc2[k+38]); wf_eff[k] = f_mask[k]*(wf2[k]-wf2[k+12])
//
// R5 post-mortem: harness d_ws poison = 41us fixed; our kernels ~27us, edge_lds
// dominated by 3 random L1-missing gathers/edge (x 40KB + eattr 40KB > 32KB L1).
// R6: stage x AND eattr in LDS next to the accumulator (119.3KB static LDS,
// gfx950 LocalMemorySize=160KB) -> all random traffic on the LDS pipe
// (~5.8cyc/ds_read, 2-way random conflicts free), global path = streamed int4 only.

#define NCL 38
#define NFL 12
#define NMAX 10240
#define EAN  10000
#define GRP 8

__device__ __forceinline__ float frcp(float v) { return __builtin_amdgcn_rcpf(v); }

// _safe_inv: 1.0 / (|v|<eps ? sign(v)*eps : v), eps=1e-2, sign(0)=+1
__device__ __forceinline__ float safe_inv(float v) {
    float den = (fabsf(v) < 0.01f) ? ((v >= 0.0f) ? 0.01f : -0.01f) : v;
    return frcp(den);
}

// 38-term edge library dotted with wc_eff on the fly (w = LDS pointer).
__device__ __forceinline__ float edge_msg(float xi, float xj, const float* w) {
    float d = xj - xi;
    float s = xj + xi;
    float acc;
    acc  = w[0] * xi + w[1] * xj + w[2] * d;
    acc += w[3] * (xi * xi) + w[4] * (xj * xj) + w[5] * (d * d);
    float ii = safe_inv(xi), ij = safe_inv(xj), id = safe_inv(d), is = safe_inv(s);
    acc += w[6] * ii + w[7] * ij + w[8] * id + w[9] * is;
    acc += w[10] * (ii * ii) + w[11] * (ij * ij) + w[12] * (id * id) + w[13] * (is * is);
    float sd = __sinf(d), cd = __cosf(d);
    float ss = __sinf(s), cs = __cosf(s);
    float si = __sinf(xi), ci = __cosf(xi);
    float sj = __sinf(xj), cj = __cosf(xj);
    acc += w[14] * sd + w[15] * cd + w[16] * ss + w[17] * cs;
    acc += w[18] * si + w[19] * ci + w[20] * sj + w[21] * cj;
    acc += w[22] * (xi * xj) + w[23] * (xi * sj) + w[24] * (xj * si) + w[25] * (sd * cs);
    {
        float e = __expf(xi), e2 = e * e;
        acc += w[26] * ((e2 - 1.f) * frcp(e2 + 1.f)) + w[27] * (e * frcp(e + 1.f)) + w[28] * fmaxf(xi, 0.f);
    }
    {
        float e = __expf(xj), e2 = e * e;
        acc += w[29] * ((e2 - 1.f) * frcp(e2 + 1.f)) + w[30] * (e * frcp(e + 1.f)) + w[31] * fmaxf(xj, 0.f);
    }
    {
        float e = __expf(d), e2 = e * e;
        acc += w[32] * ((e2 - 1.f) * frcp(e2 + 1.f)) + w[33] * (e * frcp(e + 1.f)) + w[34] * fmaxf(d, 0.f);
    }
    {
        float e = __expf(s), e2 = e * e;
        acc += w[35] * ((e2 - 1.f) * frcp(e2 + 1.f)) + w[36] * (e * frcp(e + 1.f)) + w[37] * fmaxf(s, 0.f);
    }
    return acc;
}

// Node library: [1, sin, cos, x*sin, x, x^2, inv, inv^2, inv^3, tanh, sigmoid, relu]
__device__ __forceinline__ float node_F(float v, const float* wf) {
    float sv = __sinf(v), cv = __cosf(v);
    float iv = safe_inv(v);
    float e  = __expf(v), e2 = e * e;
    float th = (e2 - 1.f) * frcp(e2 + 1.f);
    float sg = e * frcp(e + 1.f);
    return wf[0] + wf[1] * sv + wf[2] * cv + wf[3] * (v * sv)
         + wf[4] * v + wf[5] * (v * v)
         + wf[6] * iv + wf[7] * (iv * iv) + wf[8] * (iv * iv * iv)
         + wf[9] * th + wf[10] * sg + wf[11] * fmaxf(v, 0.f);
}

// ---------------- Fast path: everything random lives in LDS ----------------

__global__ void __launch_bounds__(1024) edge_lds_kernel(
        const float* __restrict__ x,
        const int* __restrict__ ei,           // [2, E] int32
        const float* __restrict__ eattr,      // [100, 100]
        const float* __restrict__ c_mask,
        const float* __restrict__ wc2,
        float* __restrict__ scratch,          // [gridDim.x, N] partials
        int E, int N) {
    __shared__ float w[NCL];
    __shared__ float acc[NMAX];               // 40 KB accumulator
    __shared__ float xs[NMAX];                // 40 KB node states
    __shared__ float ea[EAN];                 // 40 KB edge_attr (100x100)
    if (threadIdx.x < NCL)
        w[threadIdx.x] = c_mask[threadIdx.x] * (wc2[threadIdx.x] - wc2[threadIdx.x + NCL]);
    {   // zero acc (NMAX%4==0) and stage x, eattr (coalesced float4)
        float4* a4 = (float4*)acc;
        for (int i = threadIdx.x; i < NMAX / 4; i += 1024) a4[i] = make_float4(0.f, 0.f, 0.f, 0.f);
        float4* x4 = (float4*)xs;
        int nx4 = N / 4;
        const float4* gx4 = (const float4*)x;
        for (int i = threadIdx.x; i < nx4; i += 1024) x4[i] = gx4[i];
        for (int i = 4 * nx4 + threadIdx.x; i < N; i += 1024) xs[i] = x[i];
        float4* e4 = (float4*)ea;
        const float4* ge4 = (const float4*)eattr;
        for (int i = threadIdx.x; i < EAN / 4; i += 1024) e4[i] = ge4[i];
    }
    __syncthreads();

    const int T = gridDim.x * 1024;
    const int t = blockIdx.x * 1024 + threadIdx.x;
    const int E4 = E & ~3;
    for (int e0 = 4 * t; e0 < E4; e0 += 4 * T) {
        int4 s4 = *(const int4*)(ei + e0);        // 16B coalesced
        int4 d4 = *(const int4*)(ei + E + e0);    // E % 4 == 0 -> aligned
        int ss[4] = {s4.x, s4.y, s4.z, s4.w};
        int dd[4] = {d4.x, d4.y, d4.z, d4.w};
#pragma unroll
        for (int k = 0; k < 4; ++k) {
            int s = ss[k], d = dd[k];
            float m   = edge_msg(xs[d], xs[s], w);          // ds_read_b32 x2
            float eav = ea[(s % 100) * 100 + (d % 100)];    // ds_read_b32
            atomicAdd(&acc[d], eav * m);                    // ds_add_f32
        }
    }
    if (t == 0) {                                  // tail (E % 4), usually empty
        for (int e = E4; e < E; ++e) {
            int s = ei[e], d = ei[E + e];
            float m   = edge_msg(xs[d], xs[s], w);
            float eav = ea[(s % 100) * 100 + (d % 100)];
            atomicAdd(&acc[d], eav * m);
        }
    }
    __syncthreads();
    // coalesced float4 flush
    float4* dst4 = (float4*)(scratch + (size_t)blockIdx.x * N);
    const float4* a4 = (const float4*)acc;
    int n4 = N / 4;
    for (int i = threadIdx.x; i < n4; i += 1024) dst4[i] = a4[i];
    for (int i = 4 * n4 + threadIdx.x; i < N; i += 1024)
        scratch[(size_t)blockIdx.x * N + i] = acc[i];
}

// pass1: s2[g][n] = sum over this group's B/GRP partial rows
__global__ void __launch_bounds__(256) reduce1_kernel(
        const float* __restrict__ scratch, float* __restrict__ s2, int N, int B) {
    int n = blockIdx.x * 256 + threadIdx.x;
    if (n >= N) return;
    int per = B / GRP;
    const float* p = scratch + (size_t)(blockIdx.y * per) * N + n;
    float sum = 0.f;
    for (int b = 0; b < per; ++b) sum += p[(size_t)b * N];        // coalesced per iter
    s2[(size_t)blockIdx.y * N + n] = sum;
}

// pass2: out[n] = F(x[n]) + sum_g s2[g][n]   (also initializes poisoned d_out)
__global__ void __launch_bounds__(256) reduce2_kernel(
        const float* __restrict__ x,
        const float* __restrict__ f_mask,
        const float* __restrict__ wf2,
        const float* __restrict__ s2,
        float* __restrict__ out, int N) {
    __shared__ float wf[NFL];
    if (threadIdx.x < NFL)
        wf[threadIdx.x] = f_mask[threadIdx.x] * (wf2[threadIdx.x] - wf2[threadIdx.x + NFL]);
    __syncthreads();
    int n = blockIdx.x * 256 + threadIdx.x;
    if (n >= N) return;
    float sum = node_F(x[n], wf);
#pragma unroll
    for (int g = 0; g < GRP; ++g) sum += s2[(size_t)g * N + n];
    out[n] = sum;
}

// ---------------- Fallback path (R3, proven): global hw atomics ----------------

__global__ void __launch_bounds__(256) node_kernel(
        const float* __restrict__ x,
        const float* __restrict__ f_mask,
        const float* __restrict__ wf2,
        float* __restrict__ out, int n) {
    __shared__ float wf[NFL];
    if (threadIdx.x < NFL)
        wf[threadIdx.x] = f_mask[threadIdx.x] * (wf2[threadIdx.x] - wf2[threadIdx.x + NFL]);
    __syncthreads();
    int i = blockIdx.x * blockDim.x + threadIdx.x;
    if (i >= n) return;
    out[i] = node_F(x[i], wf);
}

__global__ void __launch_bounds__(256) edge_atomic_kernel(
        const float* __restrict__ x,
        const int* __restrict__ ei,
        const float* __restrict__ eattr,
        const float* __restrict__ c_mask,
        const float* __restrict__ wc2,
        float* __restrict__ out,
        int E) {
    __shared__ float w[NCL];
    if (threadIdx.x < NCL)
        w[threadIdx.x] = c_mask[threadIdx.x] * (wc2[threadIdx.x] - wc2[threadIdx.x + NCL]);
    __syncthreads();
    int t  = blockIdx.x * blockDim.x + threadIdx.x;
    int e0 = 4 * t;
    if (e0 + 3 < E) {
        int4 s4 = *(const int4*)(ei + e0);
        int4 d4 = *(const int4*)(ei + E + e0);
        int ss[4] = {s4.x, s4.y, s4.z, s4.w};
        int dd[4] = {d4.x, d4.y, d4.z, d4.w};
#pragma unroll
        for (int k = 0; k < 4; ++k) {
            int s = ss[k], d = dd[k];
            float m  = edge_msg(x[d], x[s], w);
            float ea = eattr[(s % 100) * 100 + (d % 100)];
            unsafeAtomicAdd(out + d, ea * m);
        }
    } else {
        for (int e = e0; e < E; ++e) {
            int s = ei[e], d = ei[E + e];
            float m  = edge_msg(x[d], x[s], w);
            float ea = eattr[(s % 100) * 100 + (d % 100)];
            unsafeAtomicAdd(out + d, ea * m);
        }
    }
}

extern "C" void kernel_launch(void* const* d_in, const int* in_sizes, int n_in,
                              void* d_out, int out_size, void* d_ws, size_t ws_size,
                              hipStream_t stream) {
    // inputs: 0=t, 1=x[N], 2=edge_index[2*E] int32, 3=c_mask[38], 4=f_mask[12],
    //         5=wc_2[76], 6=wf_2[24], 7=edge_attr_all[100*100]
    const float* x      = (const float*)d_in[1];
    const int*   ei     = (const int*)d_in[2];
    const float* c_mask = (const float*)d_in[3];
    const float* f_mask = (const float*)d_in[4];
    const float* wc2    = (const float*)d_in[5];
    const float* wf2    = (const float*)d_in[6];
    const float* eattr  = (const float*)d_in[7];
    float* out = (float*)d_out;

    int N = in_sizes[1];
    int E = in_sizes[2] / 2;

    // fast path needs N<=NMAX, eattr exactly 100x100, and scratch for (B+GRP) rows
    int B = 0;
    if (N <= NMAX && in_sizes[7] == EAN) {
        const int tiers[3] = {256, 128, 64};
        for (int i = 0; i < 3; ++i) {
            size_t need = ((size_t)tiers[i] + GRP) * (size_t)N * 4;
            if (ws_size >= need) { B = tiers[i]; break; }
        }
    }

    if (B) {
        float* scratch = (float*)d_ws;                 // [B][N]
        float* s2      = scratch + (size_t)B * N;      // [GRP][N]
        edge_lds_kernel<<<B, 1024, 0, stream>>>(x, ei, eattr, c_mask, wc2, scratch, E, N);
        dim3 g1((N + 255) / 256, GRP);
        reduce1_kernel<<<g1, 256, 0, stream>>>(scratch, s2, N, B);
        reduce2_kernel<<<(N + 255) / 256, 256, 0, stream>>>(x, f_mask, wf2, s2, out, N);
    } else {
        node_kernel<<<(N + 255) / 256, 256, 0, stream>>>(x, f_mask, wf2, out, N);
        int threads = (E + 3) / 4;
        edge_atomic_kernel<<<(threads + 255) / 256, 256, 0, stream>>>(x, ei, eattr, c_mask, wc2, out, E);
    }
}